// Round 2
// baseline (7254.930 us; speedup 1.0000x reference)
//
#include <hip/hip_runtime.h>

typedef unsigned short u16;
typedef unsigned int   u32;
typedef __bf16 bf16x8 __attribute__((ext_vector_type(8)));
typedef float  f32x4  __attribute__((ext_vector_type(4)));
static_assert(sizeof(bf16x8) == 16, "bf16x8 size");

#define NL   219
#define NOUT 191

__device__ const int LAGS[6] = {1, 2, 3, 7, 14, 28};

// ---- workspace layout (byte offsets). Packed weights are MFMA B-fragment order.
#define OFF_P0H 0UL
#define OFF_P0L (OFF_P0H + 2097152UL)   // cell0 pack: 128 ntile * 16 kb * 512 u16
#define OFF_P1H (OFF_P0L + 2097152UL)
#define OFF_P1L (OFF_P1H + 4194304UL)   // cell1 pack: 128 * 32 * 512 u16
#define OFF_H1H (OFF_P1L + 4194304UL)   // [2 parity][512*512] u16
#define OFF_H1L (OFF_H1H + 1048576UL)
#define OFF_H2H (OFF_H1L + 1048576UL)
#define OFF_H2L (OFF_H2H + 1048576UL)
#define OFF_H2F (OFF_H2L + 1048576UL)   // [2][512*512] f32
#define OFF_C1  (OFF_H2F + 2097152UL)   // f32
#define OFF_C2  (OFF_C1  + 1048576UL)
#define OFF_XF  (OFF_C2  + 1048576UL)   // encoder features [168][512][10] f32
#define OFF_SC  (OFF_XF  + 3440640UL)
#define OFF_LS  (OFF_SC  + 2048UL)
#define OFF_VAL (OFF_LS  + 2048UL)      // scaled series vals [512][52] f32
#define WS_NEED (OFF_VAL + 106496UL)
#define HPAR 262144UL                   // elements per parity plane

#define WSPTRS \
  u16*  p0h = (u16*)(ws + OFF_P0H); \
  u16*  p0l = (u16*)(ws + OFF_P0L); \
  u16*  p1h = (u16*)(ws + OFF_P1H); \
  u16*  p1l = (u16*)(ws + OFF_P1L); \
  u16*  h1h = (u16*)(ws + OFF_H1H); \
  u16*  h1l = (u16*)(ws + OFF_H1L); \
  u16*  h2h = (u16*)(ws + OFF_H2H); \
  u16*  h2l = (u16*)(ws + OFF_H2L); \
  float* h2f = (float*)(ws + OFF_H2F); \
  float* c1  = (float*)(ws + OFF_C1); \
  float* c2  = (float*)(ws + OFF_C2); \
  float* xf  = (float*)(ws + OFF_XF); \
  float* scp = (float*)(ws + OFF_SC); \
  float* lsp = (float*)(ws + OFF_LS); \
  float* valp = (float*)(ws + OFF_VAL); \
  (void)p0h;(void)p0l;(void)p1h;(void)p1l;(void)h1h;(void)h1l;(void)h2h;(void)h2l; \
  (void)h2f;(void)c1;(void)c2;(void)xf;(void)scp;(void)lsp;(void)valp;

__device__ __forceinline__ float sigm(float x){ return 1.f / (1.f + __expf(-x)); }
__device__ __forceinline__ float tanhx(float x){
  float ax = fabsf(x);
  float t  = __expf(-2.f * ax);
  float r  = (1.f - t) / (1.f + t);
  return copysignf(r, x);
}
__device__ __forceinline__ u16 f2bf(float x){
  u32 u = __float_as_uint(x);
  return (u16)((u + 0x7FFFu + ((u >> 16) & 1u)) >> 16);  // RNE
}
__device__ __forceinline__ float bf2f(u16 h){ return __uint_as_float(((u32)h) << 16); }

// One LSTM-cell gate GEMM tile: acc[mf][gate] over K=32*KB, 3-term bf16 split.
// A = h (bf16 hi/lo, row-major [b][512]); for KB=32 the second 16 kb read (AhiB,AloB).
template<int MF, int KB>
__device__ __forceinline__ void cell_mfma(
    const u16* __restrict__ AhiA, const u16* __restrict__ AloA,
    const u16* __restrict__ AhiB, const u16* __restrict__ AloB,
    const u16* __restrict__ phi,  const u16* __restrict__ plo,
    int R0, int jt, const float* __restrict__ bias,
    f32x4 (&acc)[MF][4])
{
  const int lane = threadIdx.x & 63;
  const int lrow = lane & 15;
  #pragma unroll
  for (int nf = 0; nf < 4; nf++){
    float bv = bias[nf * 512 + jt * 16 + lrow];
    f32x4 v = {bv, bv, bv, bv};
    #pragma unroll
    for (int mf = 0; mf < MF; mf++) acc[mf][nf] = v;
  }
  const size_t alo = (size_t)(lane >> 4) * 8;
  const size_t pb0 = (size_t)(jt * 4) * KB * 512 + (size_t)lane * 8;
  #pragma unroll 2
  for (int kb = 0; kb < KB; kb++){
    const u16* Ah; const u16* Al; int kl;
    if (KB == 16 || kb < 16){ Ah = AhiA; Al = AloA; kl = kb; }
    else                     { Ah = AhiB; Al = AloB; kl = kb - 16; }
    bf16x8 ah[MF], al[MF];
    #pragma unroll
    for (int mf = 0; mf < MF; mf++){
      size_t ao = (size_t)(R0 + mf * 16 + lrow) * 512 + (size_t)kl * 32 + alo;
      ah[mf] = *(const bf16x8*)(Ah + ao);
      al[mf] = *(const bf16x8*)(Al + ao);
    }
    bf16x8 bh[4], bl[4];
    #pragma unroll
    for (int nf = 0; nf < 4; nf++){
      size_t bo = pb0 + ((size_t)nf * KB + kb) * 512;
      bh[nf] = *(const bf16x8*)(phi + bo);
      bl[nf] = *(const bf16x8*)(plo + bo);
    }
    #pragma unroll
    for (int mf = 0; mf < MF; mf++){
      #pragma unroll
      for (int nf = 0; nf < 4; nf++){
        acc[mf][nf] = __builtin_amdgcn_mfma_f32_16x16x32_bf16(ah[mf], bh[nf], acc[mf][nf], 0, 0, 0);
        acc[mf][nf] = __builtin_amdgcn_mfma_f32_16x16x32_bf16(ah[mf], bl[nf], acc[mf][nf], 0, 0, 0);
        acc[mf][nf] = __builtin_amdgcn_mfma_f32_16x16x32_bf16(al[mf], bh[nf], acc[mf][nf], 0, 0, 0);
      }
    }
  }
}

// pointwise LSTM update; XP adds the exact fp32 K=10 x-part from LDS.
template<int MF, bool XP>
__device__ __forceinline__ void cell_epi(
    f32x4 (&acc)[MF][4], int wrowbase, int m0, int jt,
    const float* xSl, const float* WihSl,
    float* __restrict__ cst,
    u16* __restrict__ hhd, u16* __restrict__ hld, float* __restrict__ hfd)
{
  const int lane = threadIdx.x & 63;
  const int lrow = lane & 15, lkb = lane >> 4;
  const int j = jt * 16 + lrow;
  #pragma unroll
  for (int mf = 0; mf < MF; mf++){
    #pragma unroll
    for (int r = 0; r < 4; r++){
      int lr = wrowbase + mf * 16 + lkb * 4 + r;
      int b  = m0 + lr;
      float gi = acc[mf][0][r], gf = acc[mf][1][r], gg = acc[mf][2][r], go = acc[mf][3][r];
      if (XP){
        #pragma unroll
        for (int k = 0; k < 10; k++){
          float xv = xSl[lr * 10 + k];
          gi += xv * WihSl[(0 * 16 + lrow) * 10 + k];
          gf += xv * WihSl[(1 * 16 + lrow) * 10 + k];
          gg += xv * WihSl[(2 * 16 + lrow) * 10 + k];
          go += xv * WihSl[(3 * 16 + lrow) * 10 + k];
        }
      }
      size_t ci = ((size_t)b << 9) + j;
      float co = cst[ci];
      float cn = sigm(gf) * co + sigm(gi) * tanhx(gg);
      float h  = sigm(go) * tanhx(cn);
      cst[ci] = cn;
      u16 hh = f2bf(h);
      hhd[ci] = hh;
      hld[ci] = f2bf(h - bf2f(hh));
      if (hfd) hfd[ci] = h;
    }
  }
}

// ======================= prep kernels =======================
__global__ __launch_bounds__(256) void prep1(
    const float* __restrict__ X, const float* __restrict__ Whh0,
    const float* __restrict__ Wih1, const float* __restrict__ Whh1,
    unsigned char* ws)
{
  WSPTRS
  __shared__ float redS[4];
  const int tid = threadIdx.x, w = blockIdx.x;
  const int gtid = w * 256 + tid, G = 65536;
  // zero state planes
  for (int i = gtid; i < 524288; i += G){ h1h[i] = 0; h1l[i] = 0; h2h[i] = 0; h2l[i] = 0; h2f[i] = 0.f; }
  for (int i = gtid; i < 262144; i += G){ c1[i] = 0.f; c2[i] = 0.f; }
  // per-series scale (mean |x| over 168 context steps)
  {
    int rowb = w * 2 + (tid >> 7);
    int t0 = tid & 127;
    float a = fabsf(X[((size_t)rowb * NL + 28 + t0) * 3]);
    if (t0 < 40) a += fabsf(X[((size_t)rowb * NL + 156 + t0) * 3]);
    #pragma unroll
    for (int off = 1; off < 64; off <<= 1) a += __shfl_xor(a, off, 64);
    if ((tid & 63) == 0) redS[tid >> 6] = a;
    __syncthreads();
    if (tid == 0 || tid == 128){
      float s = redS[tid >> 6] + redS[(tid >> 6) + 1];
      float sc = fmaxf(s / 168.f, 0.001f);
      scp[rowb] = sc; lsp[rowb] = logf(sc);
    }
  }
  // pack cell0 B (W_hh0): linear ntile = jtile*4+gate
  for (int idx = gtid; idx < 1048576; idx += G){
    int e = idx & 7, ln = (idx >> 3) & 63, kb = (idx >> 9) & 15, nt = idx >> 13;
    int n = (nt & 3) * 512 + (nt >> 2) * 16 + (ln & 15);
    int k = kb * 32 + (ln >> 4) * 8 + e;
    float wv = Whh0[(size_t)n * 512 + k];
    u16 hh = f2bf(wv);
    p0h[idx] = hh; p0l[idx] = f2bf(wv - bf2f(hh));
  }
  // pack cell1 B ([W_ih1 ; W_hh1], K=1024)
  for (int idx = gtid; idx < 2097152; idx += G){
    int e = idx & 7, ln = (idx >> 3) & 63, kb = (idx >> 9) & 31, nt = idx >> 14;
    int n = (nt & 3) * 512 + (nt >> 2) * 16 + (ln & 15);
    int k = kb * 32 + (ln >> 4) * 8 + e;
    float wv = (k < 512) ? Wih1[(size_t)n * 512 + k] : Whh1[(size_t)n * 512 + (k - 512)];
    u16 hh = f2bf(wv);
    p1h[idx] = hh; p1l[idx] = f2bf(wv - bf2f(hh));
  }
}

__global__ __launch_bounds__(256) void prep2(const float* __restrict__ X, unsigned char* ws)
{
  WSPTRS
  const int gtid = blockIdx.x * 256 + threadIdx.x, G = 65536;
  // encoder features [t][b][10]
  for (int idx = gtid; idx < 860160; idx += G){
    int k = idx % 10; int r = idx / 10; int b = r & 511; int t = r >> 9;
    size_t xb = (size_t)b * NL;
    float v;
    if (k == 0)      v = X[(xb + 28 + t) * 3] / scp[b];
    else if (k < 3)  v = X[(xb + 28 + t) * 3 + k];
    else if (k == 3) v = lsp[b];
    else { int lag = LAGS[k - 4]; v = X[(xb + 28 + t - lag) * 3] / scp[b]; }
    xf[idx] = v;
  }
  // scaled history values for decoder lags (X times 168..195)
  for (int idx = gtid; idx < 512 * 28; idx += G){
    int b = idx / 28, v = idx % 28;
    valp[b * 52 + v] = X[((size_t)b * NL + 168 + v) * 3] / scp[b];
  }
}

// ======================= encoder step (one kernel per phase) =======================
// blocks 0..127: head y(t=p-2) by 4 sub-blocks, then cell0(t=p) [if p<=167]
// blocks 128..255: cell1(t=p-1) [if p>=1]
__global__ __launch_bounds__(256) void enc_step(
    const float* __restrict__ Wih0, const float* __restrict__ b0,
    const float* __restrict__ b1,   const float* __restrict__ Whead,
    const float* __restrict__ bhead, float* __restrict__ out,
    unsigned char* ws, int p)
{
  WSPTRS
  __shared__ float xS[1280];
  __shared__ float WihS[640];
  __shared__ float WhS[512];
  const int tid = threadIdx.x, w = blockIdx.x, wave = tid >> 6, jt = w & 31;
  const int P = p & 1;
  if (w < 128){
    const int m0 = ((w >> 5) & 3) * 128;
    if ((w & 31) == 0 && p >= 2){
      for (int i = tid; i < 512; i += 256) WhS[i] = Whead[i];
      __syncthreads();
      int t = p - 2;
      int row = tid >> 1, q = tid & 1;
      int b = m0 + row;
      const float4* h4 = (const float4*)(h2f + (size_t)P * HPAR + ((size_t)b << 9) + q * 256);
      const float4* w4 = (const float4*)(WhS + q * 256);
      float s = 0.f;
      #pragma unroll 8
      for (int i = 0; i < 64; i++){ float4 a = h4[i], bw = w4[i]; s += a.x*bw.x + a.y*bw.y + a.z*bw.z + a.w*bw.w; }
      s += __shfl_xor(s, 1, 64);
      if (q == 0) out[(size_t)b * NOUT + t] = (s + bhead[0]) * scp[b];
    }
    if (p <= 167){
      for (int i = tid; i < 640; i += 256){
        int col = i / 10, k = i % 10;
        int n = (col >> 4) * 512 + jt * 16 + (col & 15);
        WihS[i] = Wih0[n * 10 + k];
      }
      for (int i = tid; i < 1280; i += 256) xS[i] = xf[(size_t)(p * 512 + m0) * 10 + i];
      __syncthreads();
      f32x4 acc[2][4];
      cell_mfma<2,16>(h1h + (size_t)(1 - P) * HPAR, h1l + (size_t)(1 - P) * HPAR, nullptr, nullptr,
                      p0h, p0l, m0 + wave * 32, jt, b0, acc);
      cell_epi<2,true>(acc, wave * 32, m0, jt, xS, WihS, c1,
                       h1h + (size_t)P * HPAR, h1l + (size_t)P * HPAR, nullptr);
    }
  } else {
    if (p >= 1){
      const int m0 = ((w >> 5) & 3) * 128;
      f32x4 acc[2][4];
      cell_mfma<2,32>(h1h + (size_t)(1 - P) * HPAR, h1l + (size_t)(1 - P) * HPAR,
                      h2h + (size_t)P * HPAR,       h2l + (size_t)P * HPAR,
                      p1h, p1l, m0 + wave * 32, jt, b1, acc);
      cell_epi<2,false>(acc, wave * 32, m0, jt, nullptr, nullptr, c2,
                        h2h + (size_t)(1 - P) * HPAR, h2l + (size_t)(1 - P) * HPAR,
                        h2f + (size_t)(1 - P) * HPAR);
    }
  }
}

// ======================= decoder kernels =======================
// dec_cell0(d): every block computes head y for its 64 rows (jt==0 writes out col 167+d
// and valp), stages x_t (y feedback + covariates + lags), runs cell0.
__global__ __launch_bounds__(256) void dec_cell0(
    const float* __restrict__ X, const float* __restrict__ Wih0,
    const float* __restrict__ b0, const float* __restrict__ Whead,
    const float* __restrict__ bhead, float* __restrict__ out,
    unsigned char* ws, int d)
{
  WSPTRS
  __shared__ float xS[640];
  __shared__ float WihS[640];
  __shared__ float WhS[512];
  __shared__ float ylds[64];
  const int tid = threadIdx.x, w = blockIdx.x, wave = tid >> 6, jt = w & 31;
  const int m0 = (w >> 5) * 64;
  const int hp = (d + 1) & 1;
  for (int i = tid; i < 512; i += 256) WhS[i] = Whead[i];
  for (int i = tid; i < 640; i += 256){
    int col = i / 10, k = i % 10;
    int n = (col >> 4) * 512 + jt * 16 + (col & 15);
    WihS[i] = Wih0[n * 10 + k];
  }
  __syncthreads();
  { // head GEMV for own 64 rows (redundant across jt; only jt==0 writes global)
    int row = tid >> 2, q = tid & 3;
    int b = m0 + row;
    const float4* h4 = (const float4*)(h2f + (size_t)hp * HPAR + ((size_t)b << 9) + q * 128);
    const float4* w4 = (const float4*)(WhS + q * 128);
    float s = 0.f;
    #pragma unroll 8
    for (int i = 0; i < 32; i++){ float4 a = h4[i], bw = w4[i]; s += a.x*bw.x + a.y*bw.y + a.z*bw.z + a.w*bw.w; }
    s += __shfl_xor(s, 1, 64); s += __shfl_xor(s, 2, 64);
    if (q == 0){
      float y = s + bhead[0];
      ylds[row] = y;
      if (jt == 0){
        out[(size_t)b * NOUT + 167 + d] = y * scp[b];
        valp[b * 52 + 28 + d] = y;
      }
    }
  }
  __syncthreads();
  if (tid < 64){
    int b = m0 + tid;
    size_t xb = (size_t)b * NL;
    float* xr = xS + tid * 10;
    xr[0] = ylds[tid];
    xr[1] = X[(xb + 196 + d) * 3 + 1];
    xr[2] = X[(xb + 196 + d) * 3 + 2];
    xr[3] = lsp[b];
    #pragma unroll
    for (int j2 = 0; j2 < 6; j2++) xr[4 + j2] = valp[b * 52 + 28 + d - LAGS[j2]];
  }
  __syncthreads();
  f32x4 acc[1][4];
  cell_mfma<1,16>(h1h + (size_t)hp * HPAR, h1l + (size_t)hp * HPAR, nullptr, nullptr,
                  p0h, p0l, m0 + wave * 16, jt, b0, acc);
  cell_epi<1,true>(acc, wave * 16, m0, jt, xS, WihS, c1,
                   h1h + (size_t)(d & 1) * HPAR, h1l + (size_t)(d & 1) * HPAR, nullptr);
}

__global__ __launch_bounds__(256) void dec_cell1(
    const float* __restrict__ b1, unsigned char* ws, int d)
{
  WSPTRS
  const int tid = threadIdx.x, w = blockIdx.x, wave = tid >> 6, jt = w & 31;
  const int m0 = (w >> 5) * 64;
  const int hp = (d + 1) & 1;
  f32x4 acc[1][4];
  cell_mfma<1,32>(h1h + (size_t)(d & 1) * HPAR, h1l + (size_t)(d & 1) * HPAR,
                  h2h + (size_t)hp * HPAR,      h2l + (size_t)hp * HPAR,
                  p1h, p1l, m0 + wave * 16, jt, b1, acc);
  cell_epi<1,false>(acc, wave * 16, m0, jt, nullptr, nullptr, c2,
                    h2h + (size_t)(d & 1) * HPAR, h2l + (size_t)(d & 1) * HPAR,
                    h2f + (size_t)(d & 1) * HPAR);
  (void)tid;
}

// final head: y for decoder step 23 -> out col 190. h2f parity (22&1)=0.
__global__ __launch_bounds__(256) void dec_headf(
    const float* __restrict__ Whead, const float* __restrict__ bhead,
    float* __restrict__ out, unsigned char* ws)
{
  WSPTRS
  __shared__ float WhS[512];
  const int tid = threadIdx.x;
  const int m0 = blockIdx.x * 64;
  for (int i = tid; i < 512; i += 256) WhS[i] = Whead[i];
  __syncthreads();
  int row = tid >> 2, q = tid & 3;
  int b = m0 + row;
  const float4* h4 = (const float4*)(h2f + ((size_t)b << 9) + q * 128);
  const float4* w4 = (const float4*)(WhS + q * 128);
  float s = 0.f;
  #pragma unroll 8
  for (int i = 0; i < 32; i++){ float4 a = h4[i], bw = w4[i]; s += a.x*bw.x + a.y*bw.y + a.z*bw.z + a.w*bw.w; }
  s += __shfl_xor(s, 1, 64); s += __shfl_xor(s, 2, 64);
  if (q == 0) out[(size_t)b * NOUT + 190] = (s + bhead[0]) * scp[b];
}

extern "C" void kernel_launch(void* const* d_in, const int* in_sizes, int n_in,
                              void* d_out, int out_size, void* d_ws, size_t ws_size,
                              hipStream_t stream) {
  (void)in_sizes; (void)n_in; (void)out_size;
  if (ws_size < WS_NEED) return;  // fail loudly (absmax) rather than corrupt
  const float* X    = (const float*)d_in[0];
  const float* Wih0 = (const float*)d_in[4];
  const float* Whh0 = (const float*)d_in[5];
  const float* b0   = (const float*)d_in[6];
  const float* Wih1 = (const float*)d_in[7];
  const float* Whh1 = (const float*)d_in[8];
  const float* b1   = (const float*)d_in[9];
  const float* Wh   = (const float*)d_in[10];
  const float* bh   = (const float*)d_in[11];
  float* out = (float*)d_out;
  unsigned char* ws = (unsigned char*)d_ws;

  prep1<<<dim3(256), dim3(256), 0, stream>>>(X, Whh0, Wih1, Whh1, ws);
  prep2<<<dim3(256), dim3(256), 0, stream>>>(X, ws);
  for (int p = 0; p <= 168; p++)
    enc_step<<<dim3(256), dim3(256), 0, stream>>>(Wih0, b0, b1, Wh, bh, out, ws, p);
  for (int d = 0; d <= 22; d++){
    dec_cell0<<<dim3(256), dim3(256), 0, stream>>>(X, Wih0, b0, Wh, bh, out, ws, d);
    dec_cell1<<<dim3(256), dim3(256), 0, stream>>>(b1, ws, d);
  }
  dec_headf<<<dim3(8), dim3(256), 0, stream>>>(Wh, bh, out, ws);
}